// Round 5
// baseline (1003.725 us; speedup 1.0000x reference)
//
#include <hip/hip_runtime.h>
#include <hip/hip_fp16.h>
#include <hip/hip_cooperative_groups.h>

namespace cg = cooperative_groups;

// ---------------- problem constants ----------------
#define TAU_OT   0.005f
#define DELTA_OT 1e-9f
#define LOG2E    1.4426950408889634f
#define C_EPS    0.06931471805599453f   /* 0.1*ln2 : (1 - eps*K_nat) = 1 - C_EPS*K2 */
#define LM9_2    -29.897352853986263f   /* log2(1e-9) */
#define NEGI     -1.0e30f
#define SCALE_B  14.426950408889634f    /* INV_EPS * LOG2E folded into B norms */

constexpr int BB  = 64;
constexpr int DIM = 768;
constexpr int KP_H = 520;                     // K row pitch in halves (1040 B)
constexpr long KB_H = (long)512 * KP_H;       // per-batch K

// ---------------- workspace layout (float units) ----------------
constexpr size_t OFF_LENV = 0;                 // 64 int
constexpr size_t OFF_LENT = 64;                // 64 int
constexpr size_t OFF_SCAL = 128;               // 64*4: u_aug,u_m,vv_aug,vv_m
constexpr size_t OFF_LOSSA= 384;               // 64
constexpr size_t OFF_SRU  = 448;               // 64
constexpr size_t OFF_SRV  = 512;               // 64
constexpr size_t OFF_U    = 576;               // 64*512
constexpr size_t OFF_VV   = OFF_U   + 32768;   // 64*512
constexpr size_t OFF_WVA  = OFF_VV  + 32768;   // 64*512
constexpr size_t OFF_WTA  = OFF_WVA + 32768;   // 64*512
constexpr size_t OFF_KH   = OFF_WTA + 32768;   // half[64*512*520]

typedef __attribute__((ext_vector_type(8))) short short8;
typedef __attribute__((ext_vector_type(4))) float floatx4;

__device__ inline float ex2(float x){ float r; asm("v_exp_f32 %0, %1" : "=v"(r) : "v"(x)); return r; }
__device__ inline float lg2(float x){ float r; asm("v_log_f32 %0, %1" : "=v"(r) : "v"(x)); return r; }
__device__ inline unsigned cvtpk(float a, float b){
    unsigned r; asm("v_cvt_pk_bf16_f32 %0, %1, %2" : "=v"(r) : "v"(a), "v"(b)); return r;
}

// ---------------- mask dtype detection ----------------
__device__ inline int detect_mode(const unsigned char* p) {
    unsigned char b0 = p[0], b1 = p[1];
    if (b0 == 0) return 2;          // float32
    return (b1 != 0) ? 0 : 1;       // 0: u8/bool, 1: int32
}
__device__ inline int read_mask(const unsigned char* p, long idx, int mode) {
    if (mode == 0) return p[idx] != 0;
    if (mode == 1) return p[4*idx] != 0;
    return ((const float*)p)[idx] != 0.0f;
}

// batch <-> block mapping: batch b's blocks all land on XCD (b>>3)
__device__ inline void map_bs(int bid, int& b, int& s) {
    b = (bid & 7) * 8 + ((bid >> 3) & 7);
    s = bid >> 6;
}

// ---------------- lengths + init (no memset needed) ----------------
__global__ void len_init(const unsigned char* vm, const unsigned char* tm,
                         int* LENV, int* LENT, float* VV, float* SCAL,
                         float* WTA, float* LOSSA, float* SRU) {
    int b = blockIdx.x;
    bool isV = (blockIdx.y == 0);
    const unsigned char* p = isV ? vm : tm;
    int mode = detect_mode(p);
    int i = threadIdx.x;                       // 512 threads
    float s = (float)read_mask(p, (long)b*512 + i, mode);
    #pragma unroll
    for (int off = 32; off; off >>= 1) s += __shfl_xor(s, off);
    __shared__ float wsum[8];
    int w = i >> 6, lane = i & 63;
    if (lane == 0) wsum[w] = s;
    __syncthreads();
    float len = 0.f;
    #pragma unroll
    for (int q = 0; q < 8; ++q) len += wsum[q];
    int ln = (int)(len + 0.5f);
    if (isV) {
        if (i == 0) {
            LENV[b] = ln;
            SCAL[b*4+2] = 0.f; SCAL[b*4+3] = 0.f;   // vv_aug, vv_m init
            LOSSA[b] = 0.f; SRU[b] = 0.f;
        }
    } else {
        if (i == 0) LENT[b] = ln;
        VV[b*512 + i] = (i < ln) ? 0.f : NEGI;       // exp2(NEGI)=0 kills masked cols
        WTA[b*512 + i] = 0.f;
    }
}

// ---------------- bf16 MFMA batched GEMM -> K2 (fp16, *10*log2e) ----------------
// 128x128 tile, BK=32, double-buffered LDS, ONE barrier per k-iter, 3 blocks/CU.
__global__ __launch_bounds__(256, 3) void gemm_kernel(const float* __restrict__ v,
        const float* __restrict__ t, __half* __restrict__ K) {
    int bid = blockIdx.x;
    int xcd = bid & 7, kk = bid >> 3;
    int bt   = xcd * 8 + (kk >> 4);
    int tile = kk & 15;
    int m0 = (tile >> 2) * 128, n0 = (tile & 3) * 128;

    __shared__ ushort As[2][128*40];
    __shared__ ushort Bs[2][128*40];
    __shared__ float invA[128], invB[128];

    const float* vb = v + (long)bt * 512 * DIM;
    const float* tb = t + (long)bt * 512 * DIM;
    int tid = threadIdx.x;
    int w = tid >> 6, lane = tid & 63;
    int wm = (w >> 1) * 64, wn = (w & 1) * 64;
    int lrow = lane & 15, khalf = lane >> 4;
    int r0 = tid >> 3, c4 = (tid & 7) * 4;     // staging: row r0+32h, cols c4..c4+3

    const float* pa = vb + (long)(m0 + r0) * DIM + c4;
    const float* pb = tb + (long)(n0 + r0) * DIM + c4;

    float4 av[4], bv[4];
    #pragma unroll
    for (int h = 0; h < 4; ++h) {
        av[h] = *(const float4*)(pa + (long)(32*h) * DIM);
        bv[h] = *(const float4*)(pb + (long)(32*h) * DIM);
    }
    float ssA[4] = {0,0,0,0}, ssB[4] = {0,0,0,0};
    floatx4 acc[4][4] = {};

    for (int kt = 0; kt < 24; ++kt) {
        ushort* Ac = &As[kt & 1][0];
        ushort* Bc = &Bs[kt & 1][0];
        #pragma unroll
        for (int h = 0; h < 4; ++h) {
            ssA[h] += av[h].x*av[h].x + av[h].y*av[h].y + av[h].z*av[h].z + av[h].w*av[h].w;
            ssB[h] += bv[h].x*bv[h].x + bv[h].y*bv[h].y + bv[h].z*bv[h].z + bv[h].w*bv[h].w;
            uint2 ua = { cvtpk(av[h].x, av[h].y), cvtpk(av[h].z, av[h].w) };
            uint2 ub = { cvtpk(bv[h].x, bv[h].y), cvtpk(bv[h].z, bv[h].w) };
            *(uint2*)&Ac[(r0 + 32*h)*40 + c4] = ua;
            *(uint2*)&Bc[(r0 + 32*h)*40 + c4] = ub;
        }
        if (kt < 23) {                          // prefetch next k-slab into regs
            int k0 = (kt + 1) * 32;
            #pragma unroll
            for (int h = 0; h < 4; ++h) {
                av[h] = *(const float4*)(pa + (long)(32*h) * DIM + k0);
                bv[h] = *(const float4*)(pb + (long)(32*h) * DIM + k0);
            }
        }
        __syncthreads();
        short8 af[4], bf[4];
        #pragma unroll
        for (int mi = 0; mi < 4; ++mi)
            af[mi] = *(const short8*)&Ac[(wm + mi*16 + lrow)*40 + khalf*8];
        #pragma unroll
        for (int nj = 0; nj < 4; ++nj)
            bf[nj] = *(const short8*)&Bc[(wn + nj*16 + lrow)*40 + khalf*8];
        #pragma unroll
        for (int mi = 0; mi < 4; ++mi)
            #pragma unroll
            for (int nj = 0; nj < 4; ++nj)
                acc[mi][nj] = __builtin_amdgcn_mfma_f32_16x16x32_bf16(
                                  af[mi], bf[nj], acc[mi][nj], 0, 0, 0);
    }

    // fused row-norm reduce (8 threads share each row)
    #pragma unroll
    for (int h = 0; h < 4; ++h) {
        float sa = ssA[h], sb = ssB[h];
        #pragma unroll
        for (int off = 1; off < 8; off <<= 1) {
            sa += __shfl_xor(sa, off);
            sb += __shfl_xor(sb, off);
        }
        if ((tid & 7) == 0) {
            invA[r0 + 32*h] = 1.0f / fmaxf(sqrtf(sa), 1e-12f);
            invB[r0 + 32*h] = SCALE_B / fmaxf(sqrtf(sb), 1e-12f);
        }
    }
    __syncthreads();

    __half* Kb = K + (long)bt * KB_H;
    int col = lane & 15, rq = lane >> 4;        // C/D: col=lane&15, row=(lane>>4)*4+r
    #pragma unroll
    for (int nj = 0; nj < 4; ++nj) {
        int gnl = wn + nj*16 + col;
        float sn = invB[gnl];
        #pragma unroll
        for (int mi = 0; mi < 4; ++mi) {
            #pragma unroll
            for (int r = 0; r < 4; ++r) {
                int gml = wm + mi*16 + rq*4 + r;
                float val = acc[mi][nj][r] * invA[gml] * sn;
                Kb[(long)(m0+gml)*KP_H + (n0+gnl)] = __float2half(val);
            }
        }
    }
}

// ---------------- fused cooperative Sinkhorn + final + outputs ----------------
__global__ __launch_bounds__(256, 2) void sink_coop(const __half* __restrict__ K,
        float* __restrict__ U, float* __restrict__ VV, float* __restrict__ SCAL,
        const int* __restrict__ LENV, const int* __restrict__ LENT,
        float* __restrict__ WVA, float* __restrict__ WTA, float* __restrict__ LOSSA,
        float* __restrict__ SRU, float* __restrict__ SRV, float* __restrict__ out) {
    cg::grid_group grid = cg::this_grid();
    int b, s; map_bs(blockIdx.x, b, s);
    int lenv = LENV[b], lent = LENT[b];
    int tid = threadIdx.x, w = tid >> 6, lane = tid & 63;
    const __half* Kb = K + (long)b * KB_H;

    __shared__ float sv[512];
    __shared__ float aux[512];
    __shared__ float part[4][64];
    __shared__ float lw[16];

    float lmu2 = lg2(1.0f/((float)lenv + 1e-9f) + 1e-9f);
    float lnu2 = lg2(1.0f/((float)lent + 1e-9f) + 1e-9f);

    for (int it = 0; it < 5; ++it) {
        // ---------- row phase: u = lmu - lg2(sum_j 2^(K+vv) + 2^(LOG2E+vv_aug)) ----------
        {
            *(float2*)&sv[tid*2] = *(const float2*)&VV[b*512 + tid*2];
            float vv_aug = SCAL[b*4+2], vv_m = SCAL[b*4+3];
            __syncthreads();
            int base = s*64 + w*16;
            float ea = ex2(LOG2E + vv_aug);
            int nr = min(16, max(0, lenv - base));
            for (int r = 0; r < nr; ++r) {
                int i = base + r;
                const __half2* Kr = (const __half2*)(Kb + (long)i * KP_H);
                float ss = 0.f;
                #pragma unroll
                for (int c = 0; c < 4; ++c) {
                    __half2 h2 = Kr[c*64 + lane];
                    int j0 = c*128 + lane*2;
                    ss += ex2(__low2float(h2) + sv[j0]) + ex2(__high2float(h2) + sv[j0+1]);
                }
                #pragma unroll
                for (int off = 32; off; off >>= 1) ss += __shfl_xor(ss, off);
                if (lane == 0) U[b*512 + i] = lmu2 - lg2(ss + ea);
            }
            if (lane == 0)
                for (int r = nr; r < 16; ++r) U[b*512 + base + r] = NEGI;
            if (s == 0 && w == 3) {            // u_aug, u_m for the col phase
                float svv = 0.f;
                #pragma unroll
                for (int c = 0; c < 8; ++c) svv += ex2(sv[c*64 + lane]);
                #pragma unroll
                for (int off = 32; off; off >>= 1) svv += __shfl_xor(svv, off);
                if (lane == 0) {
                    float tot = svv + (float)(512 - lent)*ex2(vv_m) + ex2(vv_aug);
                    SCAL[b*4+0] = -(LOG2E + lg2(tot));
                    SCAL[b*4+1] = LM9_2 - LOG2E - vv_aug;
                }
            }
        }
        grid.sync();
        // ---------- col phase: vv = lnu - lg2(sum_i 2^(K+u) + 2^(LOG2E+u_aug)) ----------
        {
            *(float2*)&sv[tid*2] = *(const float2*)&U[b*512 + tid*2];
            float u_aug = SCAL[b*4+0], u_m = SCAL[b*4+1];
            __syncthreads();
            int j = s*64 + lane;
            int chunk = ((lenv + 31) >> 5) << 3;
            int i0 = w*chunk, i1 = min(lenv, i0 + chunk);
            const __half* p = Kb + (long)i0*KP_H + j;
            float acc = 0.f;
            int i = i0;
            for (; i + 8 <= i1; i += 8) {
                float x[8];
                #pragma unroll
                for (int q = 0; q < 8; ++q) x[q] = __half2float(p[(long)q*KP_H]) + sv[i+q];
                #pragma unroll
                for (int q = 0; q < 8; ++q) acc += ex2(x[q]);
                p += 8*KP_H;
            }
            for (; i < i1; ++i) { acc += ex2(__half2float(*p) + sv[i]); p += KP_H; }
            part[w][lane] = acc;
            __syncthreads();
            if (w == 0) {
                float tot = part[0][lane] + part[1][lane] + part[2][lane] + part[3][lane]
                          + ex2(LOG2E + u_aug);
                VV[b*512 + j] = (j < lent) ? (lnu2 - lg2(tot)) : NEGI;
            } else if (w == 1 && s == 0) {     // vv_aug, vv_m for next row phase
                float su = 0.f;
                #pragma unroll
                for (int c = 0; c < 8; ++c) su += ex2(sv[c*64 + lane]);
                #pragma unroll
                for (int off = 32; off; off >>= 1) su += __shfl_xor(su, off);
                if (lane == 0) {
                    float tot = su + (float)(512 - lenv)*ex2(u_m) + ex2(u_aug);
                    SCAL[b*4+2] = -(LOG2E + lg2(tot));
                    SCAL[b*4+3] = LM9_2 - LOG2E - u_aug;
                }
            }
        }
        grid.sync();
    }

    // ---------- final phase: T*, loss, row/col relu-sums ----------
    {
        *(float2*)&sv[tid*2] = *(const float2*)&VV[b*512 + tid*2];
        aux[tid] = 0.f; aux[tid + 256] = 0.f;
        __syncthreads();
        int base = s*64 + w*16;
        float creg[8] = {0,0,0,0,0,0,0,0};
        float lossacc = 0.f;
        int nr = min(16, max(0, lenv - base));
        for (int r = 0; r < nr; ++r) {
            int i = base + r;
            float ui = U[b*512 + i];
            const __half2* Kr = (const __half2*)(Kb + (long)i * KP_H);
            float rowacc = 0.f;
            #pragma unroll
            for (int c = 0; c < 4; ++c) {
                __half2 h2 = Kr[c*64 + lane];
                int j0 = c*128 + lane*2;
                float k0 = __low2float(h2), k1 = __high2float(h2);
                float t0 = ex2(ui + sv[j0]   + k0);
                float t1 = ex2(ui + sv[j0+1] + k1);
                lossacc += t0*(1.f - C_EPS*k0) + t1*(1.f - C_EPS*k1);
                float th0 = fmaxf(t0 - TAU_OT, 0.f), th1 = fmaxf(t1 - TAU_OT, 0.f);
                rowacc += th0 + th1;
                creg[2*c] += th0; creg[2*c+1] += th1;
            }
            #pragma unroll
            for (int off = 32; off; off >>= 1) rowacc += __shfl_xor(rowacc, off);
            if (lane == 0) WVA[b*512 + i] = rowacc;
        }
        if (lane == 0)
            for (int r = nr; r < 16; ++r) WVA[b*512 + base + r] = 0.f;
        #pragma unroll
        for (int c = 0; c < 4; ++c) {
            atomicAdd(&aux[c*128 + lane*2    ], creg[2*c]);
            atomicAdd(&aux[c*128 + lane*2 + 1], creg[2*c+1]);
        }
        #pragma unroll
        for (int off = 32; off; off >>= 1) lossacc += __shfl_xor(lossacc, off);
        if (lane == 0) lw[w] = lossacc;
        if (w == 1) {                    // Sru partial over this block's 64 rows
            float e = ex2(U[b*512 + s*64 + lane]);
            #pragma unroll
            for (int off = 32; off; off >>= 1) e += __shfl_xor(e, off);
            if (lane == 0) atomicAdd(&SRU[b], e);
        }
        if (w == 2 && s == 0) {          // Srv
            float svv = 0.f;
            #pragma unroll
            for (int c = 0; c < 8; ++c) svv += ex2(sv[c*64 + lane]);
            #pragma unroll
            for (int off = 32; off; off >>= 1) svv += __shfl_xor(svv, off);
            if (lane == 0) SRV[b] = svv;
        }
        __syncthreads();
        atomicAdd(&WTA[b*512 + tid],       aux[tid]);
        atomicAdd(&WTA[b*512 + tid + 256], aux[tid + 256]);
        if (tid == 0) atomicAdd(&LOSSA[b], lw[0]+lw[1]+lw[2]+lw[3]);
    }
    grid.sync();

    // ---------- output phase: wnorm (blocks 0..127) + loss (block 128) ----------
    if (blockIdx.x < 128) {
        int bb = blockIdx.x & 63;
        const float* num = (blockIdx.x < 64) ? WVA : WTA;
        float* dst = out + 1 + ((blockIdx.x < 64) ? 0L : (long)BB*512) + (long)bb*512;
        float v0 = num[bb*512 + tid] + DELTA_OT;
        float v1 = num[bb*512 + tid + 256] + DELTA_OT;
        float ssum = v0 + v1;
        #pragma unroll
        for (int off = 32; off; off >>= 1) ssum += __shfl_xor(ssum, off);
        if (lane == 0) lw[w] = ssum;
        __syncthreads();
        float tot = lw[0] + lw[1] + lw[2] + lw[3];
        dst[tid] = v0 / tot;
        dst[tid + 256] = v1 / tot;
    } else if (blockIdx.x == 128 && tid < 64) {
        int bq = tid;
        float u_aug = SCAL[bq*4+0], u_m = SCAL[bq*4+1];
        float vv_aug = SCAL[bq*4+2], vv_m = SCAL[bq*4+3];
        float flv = (float)LENV[bq], flt = (float)LENT[bq];
        float laug = 0.9f * ( ex2(vv_aug + LOG2E) * (SRU[bq] + (512.f - flv)*ex2(u_m))
                            + ex2(u_aug  + LOG2E) * (SRV[bq] + (512.f - flt)*ex2(vv_m))
                            + ex2(u_aug + vv_aug + LOG2E) );
        float tot = LOSSA[bq] + laug;
        #pragma unroll
        for (int off = 32; off; off >>= 1) tot += __shfl_xor(tot, off);
        if (tid == 0) out[0] = tot * (1.0f/64.0f);
    }
}

// ---------------- launch ----------------
extern "C" void kernel_launch(void* const* d_in, const int* in_sizes, int n_in,
                              void* d_out, int out_size, void* d_ws, size_t ws_size,
                              hipStream_t stream) {
    const float* v = (const float*)d_in[0];
    const float* t = (const float*)d_in[1];
    const unsigned char* vm = (const unsigned char*)d_in[2];
    const unsigned char* tm = (const unsigned char*)d_in[3];
    float* ws  = (float*)d_ws;
    float* out = (float*)d_out;

    int*   LENV = (int*)(ws + OFF_LENV);
    int*   LENT = (int*)(ws + OFF_LENT);
    float* SCAL = ws + OFF_SCAL;
    float* LOSSA= ws + OFF_LOSSA;
    float* SRU  = ws + OFF_SRU;
    float* SRV  = ws + OFF_SRV;
    float* U    = ws + OFF_U;
    float* VV   = ws + OFF_VV;
    float* WVA  = ws + OFF_WVA;
    float* WTA  = ws + OFF_WTA;
    __half* Kmat = (__half*)(ws + OFF_KH);

    len_init<<<dim3(BB, 2), 512, 0, stream>>>(vm, tm, LENV, LENT, VV, SCAL, WTA, LOSSA, SRU);
    gemm_kernel<<<dim3(1024), 256, 0, stream>>>(v, t, Kmat);

    const __half* Kc = Kmat;
    const int* LENVc = LENV;
    const int* LENTc = LENT;
    void* args[] = { (void*)&Kc, (void*)&U, (void*)&VV, (void*)&SCAL,
                     (void*)&LENVc, (void*)&LENTc, (void*)&WVA, (void*)&WTA,
                     (void*)&LOSSA, (void*)&SRU, (void*)&SRV, (void*)&out };
    hipLaunchCooperativeKernel((const void*)sink_coop, dim3(512), dim3(256),
                               args, 0, stream);
}